// Round 13
// baseline (519.280 us; speedup 1.0000x reference)
//
#include <hip/hip_runtime.h>
#include <math.h>

#define HIDN 1024
#define NHEADS 16
#define DHEAD 64
#define FFD 4096
#define LN_EPS 1e-6f
#define NEGV -1e9f

typedef __bf16 bf16_t;
typedef __bf16 bf16x8 __attribute__((ext_vector_type(8)));
typedef float f32x4 __attribute__((ext_vector_type(4)));
typedef unsigned short ushort8 __attribute__((ext_vector_type(8)));
typedef unsigned short ushort4v __attribute__((ext_vector_type(4)));

__device__ __forceinline__ unsigned short f2bf(float f) {
    unsigned u = __float_as_uint(f);
    return (unsigned short)((u + 0x7FFFu + ((u >> 16) & 1u)) >> 16);
}
__device__ __forceinline__ float bf2f(unsigned short u) {
    return __uint_as_float((unsigned)u << 16);
}
__device__ __forceinline__ void gld16(const void* g, void* l) {
    __builtin_amdgcn_global_load_lds(
        (const __attribute__((address_space(1))) void*)g,
        (__attribute__((address_space(3))) void*)l, 16, 0, 0);
}

// ---------------------------------------------------------------------------
// 128^2 bf16 MFMA GEMM (proven rounds 6-8): BK=64, 4 waves, T2 swizzle,
// double-buffered LDS with issue-early staging. Used for N<=2048 shapes.
// ---------------------------------------------------------------------------
template<int RELU>
__global__ __launch_bounds__(256)
void gemm_mfma(const bf16_t* __restrict__ A, const bf16_t* __restrict__ W,
               const float* __restrict__ ba, const float* __restrict__ bb,
               const float* __restrict__ bc, const float* __restrict__ bd,
               unsigned short* __restrict__ Cb, int M, int N, int K)
{
    __shared__ __align__(16) bf16_t As[2][128 * 64];
    __shared__ __align__(16) bf16_t Bs[2][128 * 64];

    const int tid  = threadIdx.x;
    const int wid  = tid >> 6;
    const int lane = tid & 63;
    const int m0 = blockIdx.x * 128;
    const int n0 = blockIdx.y * 128;
    const int wm = (wid & 1) * 64;
    const int wn = (wid >> 1) * 64;

    const int sr = (wid << 3) + (lane >> 3);            // 0..31
    const int sk = (((lane & 7) ^ (lane >> 3)) * 8);
    const bf16_t* pa = A + (size_t)(m0 + sr) * K + sk;
    const bf16_t* pb = W + (size_t)(n0 + sr) * K + sk;
    const int lofs = (wid << 3) * 64;

    const int lr  = lane & 15;
    const int hi_ = lane >> 4;
    const int ch0 = ((hi_ + 0) ^ (lane & 7)) * 8;   // kk = 0
    const int ch1 = ((hi_ + 4) ^ (lane & 7)) * 8;   // kk = 32

    f32x4 acc[4][4];
    #pragma unroll
    for (int i = 0; i < 4; ++i)
        #pragma unroll
        for (int j = 0; j < 4; ++j) acc[i][j] = (f32x4){0.f, 0.f, 0.f, 0.f};

    auto stage = [&](int buf, int koff) {
        #pragma unroll
        for (int c = 0; c < 4; ++c) {
            gld16(pa + (size_t)c * 32 * K + koff, &As[buf][lofs + c * 32 * 64]);
            gld16(pb + (size_t)c * 32 * K + koff, &Bs[buf][lofs + c * 32 * 64]);
        }
    };
    auto compute = [&](int buf) {
        const bf16_t* fa = &As[buf][(wm + lr) * 64];
        const bf16_t* fb = &Bs[buf][(wn + lr) * 64];
        #pragma unroll
        for (int kk = 0; kk < 2; ++kk) {
            const int ch = kk ? ch1 : ch0;
            bf16x8 a[4], b[4];
            #pragma unroll
            for (int i = 0; i < 4; ++i) {
                a[i] = *(const bf16x8*)(fa + i * 16 * 64 + ch);
                b[i] = *(const bf16x8*)(fb + i * 16 * 64 + ch);
            }
            #pragma unroll
            for (int i = 0; i < 4; ++i)
                #pragma unroll
                for (int j = 0; j < 4; ++j)
                    acc[i][j] = __builtin_amdgcn_mfma_f32_16x16x32_bf16(
                        a[i], b[j], acc[i][j], 0, 0, 0);
        }
    };

    stage(0, 0);
    asm volatile("s_waitcnt vmcnt(0)" ::: "memory");
    __syncthreads();

    for (int k0 = 0; k0 < K; k0 += 128) {
        if (k0 + 64 < K) stage(1, k0 + 64);
        compute(0);
        asm volatile("s_waitcnt vmcnt(0)" ::: "memory");
        __syncthreads();
        if (k0 + 128 < K) stage(0, k0 + 128);
        compute(1);
        asm volatile("s_waitcnt vmcnt(0)" ::: "memory");
        __syncthreads();
    }

    const int seg = n0 >> 10;
    const float* bias = (seg == 0) ? ba : (seg == 1) ? bb : (seg == 2) ? bc : bd;
    const int nl = (n0 & 1023);
    const int er = wm + (lane >> 4) * 4;
    const int ec = wn + (lane & 15);
    float bv[4];
    #pragma unroll
    for (int j = 0; j < 4; ++j) bv[j] = bias[nl + ec + j * 16];
    #pragma unroll
    for (int i = 0; i < 4; ++i)
        #pragma unroll
        for (int j = 0; j < 4; ++j)
            #pragma unroll
            for (int r = 0; r < 4; ++r) {
                float v = acc[i][j][r] + bv[j];
                if (RELU) v = fmaxf(v, 0.f);
                Cb[(size_t)(m0 + er + i * 16 + r) * N + (n0 + ec + j * 16)] = f2bf(v);
            }
}

// ---------------------------------------------------------------------------
// 256^2 bf16 MFMA GEMM, round 13: pair-iteration counted-vmcnt schedule.
// BK=64 (r11's zero-conflict chunk-XOR swizzle). Iteration = 2 K-tiles
// (buf0/buf1), 8 phases of {ds_read regs -> barrier -> lgkm0 -> 16 MFMA ->
// barrier}. Issue rotation so every wait has 4 newer loads in flight:
//   P0: issue B(t+1);  P3-end: issue A(t+2) THEN vmcnt(4) (waits A/B(t+1));
//   P4: issue B(t+2);  P7-end: issue A(t+3) THEN vmcnt(4) (waits A/B(t+2)).
// Steady-state lead = 4-8 phases (~1000+ cyc >= HBM latency); vmcnt(0) only
// in the final pair. WAR: every stage targets a buffer whose readers all
// passed the immediately preceding barrier. Accumulation order == r11
// (bit-identical output). Requires M==8192, N%256==0, (N/256)%2==0, K%128==0.
// ---------------------------------------------------------------------------
#define MFMA16(F0, F1, F2, F3)                                                      \
    acc[F0][0] = __builtin_amdgcn_mfma_f32_16x16x32_bf16(a0, b0, acc[F0][0], 0,0,0); \
    acc[F0][1] = __builtin_amdgcn_mfma_f32_16x16x32_bf16(a0, b1, acc[F0][1], 0,0,0); \
    acc[F0][2] = __builtin_amdgcn_mfma_f32_16x16x32_bf16(a0, b2, acc[F0][2], 0,0,0); \
    acc[F0][3] = __builtin_amdgcn_mfma_f32_16x16x32_bf16(a0, b3, acc[F0][3], 0,0,0); \
    acc[F1][0] = __builtin_amdgcn_mfma_f32_16x16x32_bf16(a1, b0, acc[F1][0], 0,0,0); \
    acc[F1][1] = __builtin_amdgcn_mfma_f32_16x16x32_bf16(a1, b1, acc[F1][1], 0,0,0); \
    acc[F1][2] = __builtin_amdgcn_mfma_f32_16x16x32_bf16(a1, b2, acc[F1][2], 0,0,0); \
    acc[F1][3] = __builtin_amdgcn_mfma_f32_16x16x32_bf16(a1, b3, acc[F1][3], 0,0,0); \
    acc[F2][0] = __builtin_amdgcn_mfma_f32_16x16x32_bf16(a2, b0, acc[F2][0], 0,0,0); \
    acc[F2][1] = __builtin_amdgcn_mfma_f32_16x16x32_bf16(a2, b1, acc[F2][1], 0,0,0); \
    acc[F2][2] = __builtin_amdgcn_mfma_f32_16x16x32_bf16(a2, b2, acc[F2][2], 0,0,0); \
    acc[F2][3] = __builtin_amdgcn_mfma_f32_16x16x32_bf16(a2, b3, acc[F2][3], 0,0,0); \
    acc[F3][0] = __builtin_amdgcn_mfma_f32_16x16x32_bf16(a3, b0, acc[F3][0], 0,0,0); \
    acc[F3][1] = __builtin_amdgcn_mfma_f32_16x16x32_bf16(a3, b1, acc[F3][1], 0,0,0); \
    acc[F3][2] = __builtin_amdgcn_mfma_f32_16x16x32_bf16(a3, b2, acc[F3][2], 0,0,0); \
    acc[F3][3] = __builtin_amdgcn_mfma_f32_16x16x32_bf16(a3, b3, acc[F3][3], 0,0,0);

#define READ_A(BUF, FB, CC)                                      \
    a0 = ldAf(BUF, (FB)+0, CC); a1 = ldAf(BUF, (FB)+1, CC);       \
    a2 = ldAf(BUF, (FB)+2, CC); a3 = ldAf(BUF, (FB)+3, CC);
#define READ_B(BUF, CC)                                          \
    b0 = ldBf(BUF, 0, CC); b1 = ldBf(BUF, 1, CC);                 \
    b2 = ldBf(BUF, 2, CC); b3 = ldBf(BUF, 3, CC);
#define PHASE_MID()                                              \
    __builtin_amdgcn_s_barrier();                                \
    asm volatile("s_waitcnt lgkmcnt(0)" ::: "memory");           \
    __builtin_amdgcn_sched_barrier(0);                           \
    __builtin_amdgcn_s_setprio(1);
#define PHASE_END()                                              \
    __builtin_amdgcn_s_setprio(0);                               \
    __builtin_amdgcn_s_barrier();

template<int RELU>
__global__ __launch_bounds__(512, 1)
void gemm_mfma256(const bf16_t* __restrict__ A, const bf16_t* __restrict__ W,
                  const float* __restrict__ ba, const float* __restrict__ bb,
                  const float* __restrict__ bc, const float* __restrict__ bd,
                  unsigned short* __restrict__ Cb, int M, int N, int K)
{
    __shared__ __align__(16) bf16_t As[2][256 * 64];
    __shared__ __align__(16) bf16_t Bs[2][256 * 64];

    const int tid  = threadIdx.x;
    const int wid  = tid >> 6;        // 0..7
    const int lane = tid & 63;
    const int lo   = lane & 15;
    const int hi   = lane >> 4;

    // XCD-aware 2D-chunk swizzle (GX == 32 required): xcd owns (8 x GY/2).
    const int GY = gridDim.y;
    const int id = blockIdx.y * gridDim.x + blockIdx.x;
    const int xcd = id & 7;
    const int c   = id >> 3;
    const int CN  = GY >> 1;
    const int m0 = (((xcd & 3) << 3) + (c & 7)) * 256;
    const int n0 = ((xcd >> 2) * CN + (c >> 3)) * 256;

    const int wm = (wid & 1) * 128;   // wave M offset
    const int wn = (wid >> 1) * 64;   // wave N offset

    const int srow = tid >> 3;                           // 0..63
    const int ssk  = (((tid & 7) ^ (srow & 7)) * 8);     // pre-swizzled source
    const bf16_t* pa = A + (size_t)(m0 + srow) * K + ssk;
    const bf16_t* pb = W + (size_t)(n0 + srow) * K + ssk;
    const int lbase = (wid << 3) * 64;

    auto stageA = [&](int buf, int koff) {
        #pragma unroll
        for (int i = 0; i < 4; ++i)
            gld16(pa + (size_t)i * 64 * K + koff, &As[buf][i * 64 * 64 + lbase]);
    };
    auto stageB = [&](int buf, int koff) {
        #pragma unroll
        for (int i = 0; i < 4; ++i)
            gld16(pb + (size_t)i * 64 * K + koff, &Bs[buf][i * 64 * 64 + lbase]);
    };
    auto ldAf = [&](int buf, int f, int cc) -> bf16x8 {
        const int row = wm + f * 16 + lo;
        const int ch  = ((cc * 4 + hi) ^ (lo & 7)) * 8;
        return *(const bf16x8*)&As[buf][row * 64 + ch];
    };
    auto ldBf = [&](int buf, int g, int cc) -> bf16x8 {
        const int row = wn + g * 16 + lo;
        const int ch  = ((cc * 4 + hi) ^ (lo & 7)) * 8;
        return *(const bf16x8*)&Bs[buf][row * 64 + ch];
    };

    f32x4 acc[8][4];
    #pragma unroll
    for (int f = 0; f < 8; ++f)
        #pragma unroll
        for (int g = 0; g < 4; ++g) acc[f][g] = (f32x4){0.f, 0.f, 0.f, 0.f};

    const int nt = K >> 6;   // even (K%128==0)

    // prologue: A(0),B(0) -> buf0; A(1) -> buf1; wait A(0),B(0), A(1) flying.
    stageA(0, 0);
    stageB(0, 0);
    stageA(1, 64);
    asm volatile("s_waitcnt vmcnt(4)" ::: "memory");
    __builtin_amdgcn_s_barrier();

    for (int t = 0; t < nt; t += 2) {
        bf16x8 a0, a1, a2, a3, b0, b1, b2, b3;
        const int kB1 = (t + 1) << 6;

        // ---- P0: buf0 kc0 mh0; issue B(t+1) ----
        READ_A(0, 0, 0); READ_B(0, 0);
        stageB(1, kB1);
        PHASE_MID(); MFMA16(0, 1, 2, 3); PHASE_END();
        // ---- P1: buf0 kc0 mh1 (reuse b) ----
        READ_A(0, 4, 0);
        PHASE_MID(); MFMA16(4, 5, 6, 7); PHASE_END();
        // ---- P2: buf0 kc1 mh0 ----
        READ_A(0, 0, 1); READ_B(0, 1);
        PHASE_MID(); MFMA16(0, 1, 2, 3); PHASE_END();
        // ---- P3: buf0 kc1 mh1 ----
        READ_A(0, 4, 1);
        PHASE_MID(); MFMA16(4, 5, 6, 7); PHASE_END();
        // P3-end: buf0 fully read. Issue A(t+2)->buf0, counted wait for
        // A(t+1),B(t+1) (leaves A(t+2) in flight). Barrier -> buf1 ready.
        if (t + 2 < nt) {
            stageA(0, (t + 2) << 6);
            asm volatile("s_waitcnt vmcnt(4)" ::: "memory");
        } else {
            asm volatile("s_waitcnt vmcnt(0)" ::: "memory");
        }
        __builtin_amdgcn_s_barrier();

        // ---- P4: buf1 kc0 mh0; issue B(t+2) ----
        READ_A(1, 0, 0); READ_B(1, 0);
        if (t + 2 < nt) stageB(0, (t + 2) << 6);
        PHASE_MID(); MFMA16(0, 1, 2, 3); PHASE_END();
        // ---- P5: buf1 kc0 mh1 ----
        READ_A(1, 4, 0);
        PHASE_MID(); MFMA16(4, 5, 6, 7); PHASE_END();
        // ---- P6: buf1 kc1 mh0 ----
        READ_A(1, 0, 1); READ_B(1, 1);
        PHASE_MID(); MFMA16(0, 1, 2, 3); PHASE_END();
        // ---- P7: buf1 kc1 mh1 ----
        READ_A(1, 4, 1);
        PHASE_MID(); MFMA16(4, 5, 6, 7); PHASE_END();
        // P7-end: buf1 fully read. Issue A(t+3)->buf1, counted wait for
        // A(t+2),B(t+2). Barrier -> buf0 ready for next pair.
        if (t + 3 < nt) {
            stageA(1, (t + 3) << 6);
            asm volatile("s_waitcnt vmcnt(4)" ::: "memory");
        } else {
            asm volatile("s_waitcnt vmcnt(0)" ::: "memory");
        }
        __builtin_amdgcn_s_barrier();
    }

    // epilogue
    const int seg = n0 >> 10;
    const float* bias = (seg == 0) ? ba : (seg == 1) ? bb : (seg == 2) ? bc : bd;
    const int nl = (n0 & 1023);
    float bv[4];
    #pragma unroll
    for (int g = 0; g < 4; ++g) bv[g] = bias[nl + wn + g * 16 + lo];
    #pragma unroll
    for (int f = 0; f < 8; ++f)
        #pragma unroll
        for (int g = 0; g < 4; ++g)
            #pragma unroll
            for (int r = 0; r < 4; ++r) {
                float v = acc[f][g][r] + bv[g];
                if (RELU) v = fmaxf(v, 0.f);
                Cb[(size_t)(m0 + wm + f * 16 + hi * 4 + r) * N
                   + (n0 + wn + g * 16 + lo)] = f2bf(v);
            }
}

// ---------------------------------------------------------------------------
// MFMA attention v2 (unchanged round 8): one block per (head,batch), 8 waves,
// K/V fetched once, swizzled LDS, async-STAGE split.
// ---------------------------------------------------------------------------
template<int HAS_MASK>
__global__ __launch_bounds__(512, 2)
void attn_mfma(const bf16_t* __restrict__ Q, const bf16_t* __restrict__ K,
               const bf16_t* __restrict__ V, int qstride, int kvstride,
               const int* __restrict__ mask,
               unsigned short* __restrict__ O, int Lk)
{
    __shared__ __align__(16) unsigned short Ks[64][72];    // [k][d] swz
    __shared__ __align__(16) unsigned short Vt[64][72];    // [d][k] swz
    __shared__ __align__(16) unsigned short Ps[128][72];   // [q][k] linear
    __shared__ int smask[64];

    const int tid  = threadIdx.x;
    const int wid  = tid >> 6;
    const int lane = tid & 63;
    const int lo   = lane & 15;
    const int hi   = lane >> 4;
    const int h    = blockIdx.x;
    const int b    = blockIdx.y;
    const int Lq   = 512;

    bf16x8 qf[4][2];
    #pragma unroll
    for (int s4 = 0; s4 < 4; ++s4) {
        const bf16_t* qp = Q + (size_t)(b*Lq + s4*128 + wid*16 + lo) * qstride
                             + h*DHEAD + hi*8;
        qf[s4][0] = *(const bf16x8*)qp;
        qf[s4][1] = *(const bf16x8*)(qp + 32);
    }

    float mrun[4][4], lrun[4][4];
    f32x4 Oc[4][4];
    #pragma unroll
    for (int s4 = 0; s4 < 4; ++s4)
        #pragma unroll
        for (int r = 0; r < 4; ++r) {
            mrun[s4][r] = -INFINITY; lrun[s4][r] = 0.f;
            Oc[s4][r] = (f32x4){0.f, 0.f, 0.f, 0.f};
        }

    ushort8 r0, r1;
    int mreg = 0;

    auto load_tile = [&](int k0) {
        if (tid < 256) {
            const int sr = tid >> 2, sc = (tid & 3) * 16;
            const unsigned short* kp = (const unsigned short*)
                (K + (size_t)(b*Lk + k0 + sr) * kvstride + h*DHEAD + sc);
            r0 = *(const ushort8*)kp;
            r1 = *(const ushort8*)(kp + 8);
        } else {
            const int t2 = tid - 256, sr = t2 >> 2, sc = (t2 & 3) * 16;
            const unsigned short* vp = (const unsigned short*)
                (V + (size_t)(b*Lk + k0 + sr) * kvstride + h*DHEAD + sc);
            r0 = *(const ushort8*)vp;
            r1 = *(const ushort8*)(vp + 8);
        }
        if (HAS_MASK && tid < 64) mreg = mask[b*Lk + k0 + tid];
    };
    auto store_tile = [&]() {
        if (tid < 256) {
            const int sr = tid >> 2, sc = (tid & 3) * 16;
            const int x = ((sr >> 3) & 7) << 3;
            *(ushort8*)&Ks[sr][sc ^ x]       = r0;
            *(ushort8*)&Ks[sr][(sc + 8) ^ x] = r1;
        } else {
            const int t2 = tid - 256, sr = t2 >> 2, sc = (t2 & 3) * 16;
            #pragma unroll
            for (int t = 0; t < 8; ++t) {
                const int d0 = sc + t, d1 = sc + 8 + t;
                Vt[d0][sr ^ (((d0 >> 3) & 7) << 3)] = r0[t];
                Vt[d1][sr ^ (((d1 >> 3) & 7) << 3)] = r1[t];
            }
        }
        if (HAS_MASK && tid < 64) smask[tid] = mreg;
    };

    load_tile(0);
    store_tile();
    __syncthreads();

    int k0 = 0;
    while (true) {
        const bool more = (k0 + 64 < Lk);
        if (more) load_tile(k0 + 64);

        #pragma unroll
        for (int s4 = 0; s4 < 4; ++s4) {
            f32x4 sv[4];
            #pragma unroll
            for (int j = 0; j < 4; ++j) sv[j] = (f32x4){0.f, 0.f, 0.f, 0.f};
            #pragma unroll
            for (int kk = 0; kk < 2; ++kk) {
                #pragma unroll
                for (int j = 0; j < 4; ++j) {
                    const int krow = j*16 + lo;
                    const int kcol = (kk*32 + hi*8) ^ (((krow >> 3) & 7) << 3);
                    bf16x8 bfrag = *(const bf16x8*)&Ks[krow][kcol];
                    sv[j] = __builtin_amdgcn_mfma_f32_16x16x32_bf16(
                        qf[s4][kk], bfrag, sv[j], 0, 0, 0);
                }
            }
            #pragma unroll
            for (int j = 0; j < 4; ++j) {
                bool msk = HAS_MASK ? (smask[j*16 + lo] != 0) : false;
                #pragma unroll
                for (int r = 0; r < 4; ++r) {
                    float x = sv[j][r] * 0.125f;
                    sv[j][r] = msk ? NEGV : x;
                }
            }
            #pragma unroll
            for (int r = 0; r < 4; ++r) {
                float tm = fmaxf(fmaxf(sv[0][r], sv[1][r]), fmaxf(sv[2][r], sv[3][r]));
                #pragma unroll
                for (int m = 1; m < 16; m <<= 1) tm = fmaxf(tm, __shfl_xor(tm, m));
                float mnew = fmaxf(mrun[s4][r], tm);
                float f = __expf(mrun[s4][r] - mnew);
                float ps = 0.f;
                #pragma unroll
                for (int j = 0; j < 4; ++j) {
                    float p = __expf(sv[j][r] - mnew);
                    sv[j][r] = p;
                    ps += p;
                }
                #pragma unroll
                for (int m = 1; m < 16; m <<= 1) ps += __shfl_xor(ps, m);
                lrun[s4][r] = lrun[s4][r] * f + ps;
                mrun[s4][r] = mnew;
                #pragma unroll
                for (int n = 0; n < 4; ++n) Oc[s4][n][r] *= f;
                #pragma unroll
                for (int j = 0; j < 4; ++j)
                    Ps[wid*16 + hi*4 + r][j*16 + lo] = f2bf(sv[j][r]);
            }
            #pragma unroll
            for (int kk = 0; kk < 2; ++kk) {
                bf16x8 pa = *(const bf16x8*)&Ps[wid*16 + lo][kk*32 + hi*8];
                #pragma unroll
                for (int n = 0; n < 4; ++n) {
                    const int vrow = n*16 + lo;
                    const int vcol = (kk*32 + hi*8) ^ (((vrow >> 3) & 7) << 3);
                    bf16x8 vf = *(const bf16x8*)&Vt[vrow][vcol];
                    Oc[s4][n] = __builtin_amdgcn_mfma_f32_16x16x32_bf16(
                        pa, vf, Oc[s4][n], 0, 0, 0);
                }
            }
        }

        if (!more) break;
        __syncthreads();
        store_tile();
        __syncthreads();
        k0 += 64;
    }

    #pragma unroll
    for (int s4 = 0; s4 < 4; ++s4)
        #pragma unroll
        for (int r = 0; r < 4; ++r) {
            float inv = 1.f / lrun[s4][r];
            const size_t row = (size_t)(b*Lq + s4*128 + wid*16 + hi*4 + r) * HIDN
                             + h*DHEAD;
            #pragma unroll
            for (int n = 0; n < 4; ++n)
                O[row + n*16 + lo] = f2bf(Oc[s4][n][r] * inv);
        }
}

// ---------------------------------------------------------------------------
// LayerNorm(X + R): X,R bf16; stats fp32; write bf16 (in-place ok) and/or f32.
// ---------------------------------------------------------------------------
template<int WF32, int WBF>
__global__ __launch_bounds__(256)
void ln_res_b(const unsigned short* __restrict__ X, const unsigned short* __restrict__ R,
              const float* __restrict__ G, const float* __restrict__ Bv,
              unsigned short* __restrict__ OutB, float* __restrict__ OutF)
{
    const int row = blockIdx.x;
    const int tid = threadIdx.x;
    const size_t base = (size_t)row * HIDN + tid * 4;
    ushort4v xv = *(const ushort4v*)(X + base);
    ushort4v rv = *(const ushort4v*)(R + base);
    float y[4];
    #pragma unroll
    for (int t = 0; t < 4; ++t) y[t] = bf2f(xv[t]) + bf2f(rv[t]);
    float s1 = y[0] + y[1] + y[2] + y[3];
    float s2 = y[0]*y[0] + y[1]*y[1] + y[2]*y[2] + y[3]*y[3];
    #pragma unroll
    for (int m = 1; m < 64; m <<= 1) {
        s1 += __shfl_xor(s1, m);
        s2 += __shfl_xor(s2, m);
    }
    __shared__ float red1[4], red2[4];
    const int wave = tid >> 6, lane = tid & 63;
    if (lane == 0) { red1[wave] = s1; red2[wave] = s2; }
    __syncthreads();
    s1 = red1[0] + red1[1] + red1[2] + red1[3];
    s2 = red2[0] + red2[1] + red2[2] + red2[3];
    const float mean = s1 * (1.f / HIDN);
    const float var  = s2 * (1.f / HIDN) - mean * mean;
    const float inv  = rsqrtf(var + LN_EPS);
    float4 gv = *(const float4*)(G + tid*4);
    float4 bv = *(const float4*)(Bv + tid*4);
    float o[4];
    o[0] = gv.x * (y[0]-mean) * inv + bv.x;
    o[1] = gv.y * (y[1]-mean) * inv + bv.y;
    o[2] = gv.z * (y[2]-mean) * inv + bv.z;
    o[3] = gv.w * (y[3]-mean) * inv + bv.w;
    if (WBF) {
        ushort4v ob;
        #pragma unroll
        for (int t = 0; t < 4; ++t) ob[t] = f2bf(o[t]);
        *(ushort4v*)(OutB + base) = ob;
    }
    if (WF32) {
        float4 of = {o[0], o[1], o[2], o[3]};
        *(float4*)(OutF + base) = of;
    }
}

// ---------------------------------------------------------------------------
// One-shot fp32 -> bf16 conversion of 1Mi-element units (weights + acts).
// ---------------------------------------------------------------------------
struct CvtArgs {
    const float* src[32];
    unsigned short* dst[32];
};

__global__ __launch_bounds__(256)
void cvt_units(CvtArgs args)
{
    const float* s = args.src[blockIdx.y];
    unsigned short* d = args.dst[blockIdx.y];
    const int i = blockIdx.x * 256 + threadIdx.x;   // 0..131071
    const float4* p = (const float4*)s + (size_t)i * 2;
    float4 a = p[0], b = p[1];
    ushort8 o;
    o[0] = f2bf(a.x); o[1] = f2bf(a.y); o[2] = f2bf(a.z); o[3] = f2bf(a.w);
    o[4] = f2bf(b.x); o[5] = f2bf(b.y); o[6] = f2bf(b.z); o[7] = f2bf(b.w);
    ((ushort8*)d)[i] = o;
}

// ---------------------------------------------------------------------------
extern "C" void kernel_launch(void* const* d_in, const int* in_sizes, int n_in,
                              void* d_out, int out_size, void* d_ws, size_t ws_size,
                              hipStream_t stream)
{
    const float* img   = (const float*)d_in[0];
    const float* ques  = (const float*)d_in[1];
    const float* kg    = (const float*)d_in[2];
    const int*   qmask = (const int*)d_in[3];
    const int*   kmask = (const int*)d_in[4];
    const float* qw = (const float*)d_in[5];
    const float* qb = (const float*)d_in[6];
    const float* kw = (const float*)d_in[7];
    const float* kb = (const float*)d_in[8];
    const float* vw = (const float*)d_in[9];
    const float* vb = (const float*)d_in[10];
    const float* ow = (const float*)d_in[11];
    const float* ob = (const float*)d_in[12];
    const float* w1 = (const float*)d_in[13];
    const float* b1 = (const float*)d_in[14];
    const float* w2 = (const float*)d_in[15];
    const float* b2 = (const float*)d_in[16];
    const float* lng = (const float*)d_in[17];
    const float* lnb = (const float*)d_in[18];
    float* out = (float*)d_out;

    const int B = 16;
    const int NX = B * 512;                    // 8192 rows
    const size_t WSTEP = (size_t)1024 * 1024;
    const size_t MB = (size_t)1 << 20;
    const size_t MELEM = (size_t)1024 * 1024;

    char* wsb = (char*)d_ws;
    unsigned short* xb    = (unsigned short*)(wsb);            // 16 MB
    unsigned short* bM    = (unsigned short*)(wsb + 16*MB);    // 16 MB
    unsigned short* bOb   = (unsigned short*)(wsb + 32*MB);    // 16 MB
    unsigned short* quesb = (unsigned short*)(wsb + 48*MB);    //  2 MB
    unsigned short* kgb   = (unsigned short*)(wsb + 50*MB);    //  4 MB
    unsigned short* wa    = (unsigned short*)(wsb + 56*MB);    // 40 MB weight arena
    unsigned short* bQKV  = (unsigned short*)(wsb + 96*MB);    // 48 MB
    unsigned short* bKV   = (unsigned short*)(wsb + 144*MB);   //  8 MB
    unsigned short* hb    = (unsigned short*)(wsb + 96*MB);    // 64 MB, overlays bQKV/bKV

    CvtArgs ca;
    int u = 0;
    auto addu = [&](const float* src, int melems, unsigned short* dst) {
        for (int i = 0; i < melems; ++i) {
            ca.src[u] = src + (size_t)i * MELEM;
            ca.dst[u] = dst + (size_t)i * MELEM;
            ++u;
        }
    };
    addu(qw + 0*WSTEP, 1, wa + 0*MELEM);
    addu(kw + 0*WSTEP, 1, wa + 1*MELEM);
    addu(vw + 0*WSTEP, 1, wa + 2*MELEM);
    addu(qw + 1*WSTEP, 1, wa + 3*MELEM);
    addu(kw + 1*WSTEP, 1, wa + 4*MELEM);
    addu(vw + 1*WSTEP, 1, wa + 5*MELEM);
    addu(qw + 2*WSTEP, 1, wa + 6*MELEM);
    addu(kw + 2*WSTEP, 1, wa + 7*MELEM);
    addu(vw + 2*WSTEP, 1, wa + 8*MELEM);
    addu(ow + 0*WSTEP, 1, wa + 9*MELEM);
    addu(ow + 1*WSTEP, 1, wa + 10*MELEM);
    addu(ow + 2*WSTEP, 1, wa + 11*MELEM);
    addu(w1, 4, wa + 12*MELEM);
    addu(w2, 4, wa + 16*MELEM);
    addu(img,  8, xb);
    addu(ques, 1, quesb);
    addu(kg,   2, kgb);

    dim3 blk(256);
    cvt_units<<<dim3(512, u), blk, 0, stream>>>(ca);

    auto gemm = [&](const unsigned short* A, const unsigned short* W,
                    const float* ba, const float* bb_, const float* bc, const float* bd,
                    unsigned short* C, int M, int N, int K, int relu) {
        // 256^2 pair-schedule kernel for the big shapes (M==8192 only)
        if (N >= 3072 && M == 8192 && (N % 256) == 0
            && ((N / 256) % 2) == 0 && (K % 128) == 0) {
            dim3 grid(M / 256, N / 256);
            if (relu) gemm_mfma256<1><<<grid, dim3(512), 0, stream>>>(
                (const bf16_t*)A, (const bf16_t*)W, ba, bb_, bc, bd, C, M, N, K);
            else      gemm_mfma256<0><<<grid, dim3(512), 0, stream>>>(
                (const bf16_t*)A, (const bf16_t*)W, ba, bb_, bc, bd, C, M, N, K);
            return;
        }
        dim3 grid(M / 128, N / 128);
        if (relu) gemm_mfma<1><<<grid, blk, 0, stream>>>(
            (const bf16_t*)A, (const bf16_t*)W, ba, bb_, bc, bd, C, M, N, K);
        else      gemm_mfma<0><<<grid, blk, 0, stream>>>(
            (const bf16_t*)A, (const bf16_t*)W, ba, bb_, bc, bd, C, M, N, K);
    };

    const unsigned short* Akv[3] = {xb, quesb, kgb};
    const int Mkv[3] = {NX, B * 64, B * 128};
    const int Lk[3]  = {512, 64, 128};

    dim3 ablk(512);
    dim3 agrid(NHEADS, B);

    for (int t = 0; t < 3; ++t) {
        if (t == 0) {
            gemm(xb, wa + 0*MELEM, qb + 0, kb + 0, vb + 0, vb + 0,
                 bQKV, NX, 3072, 1024, 0);
            attn_mfma<0><<<agrid, ablk, 0, stream>>>(
                (const bf16_t*)bQKV, (const bf16_t*)bQKV + 1024, (const bf16_t*)bQKV + 2048,
                3072, 3072, nullptr, bOb, Lk[t]);
        } else {
            gemm(xb, wa + (t == 1 ? 3 : 6)*MELEM,
                 qb + t*1024, qb + t*1024, qb + t*1024, qb + t*1024,
                 bQKV, NX, 1024, 1024, 0);
            gemm(Akv[t], wa + (t == 1 ? 4 : 7)*MELEM,
                 kb + t*1024, vb + t*1024, vb + t*1024, vb + t*1024,
                 bKV, Mkv[t], 2048, 1024, 0);
            attn_mfma<1><<<agrid, ablk, 0, stream>>>(
                (const bf16_t*)bQKV, (const bf16_t*)bKV, (const bf16_t*)bKV + 1024,
                1024, 2048, (t == 1 ? qmask : kmask), bOb, Lk[t]);
        }
        gemm(bOb, wa + (9 + t)*MELEM,
             ob + t*1024, ob + t*1024, ob + t*1024, ob + t*1024,
             bM, NX, 1024, 1024, 0);
        ln_res_b<0,1><<<NX, blk, 0, stream>>>(xb, bM, lng + t*1024, lnb + t*1024, xb, nullptr);
    }

    // FFN
    gemm(xb, wa + 12*MELEM, b1, b1 + 1024, b1 + 2048, b1 + 3072, hb, NX, FFD, 1024, 1);
    gemm(hb, wa + 16*MELEM, b2, b2, b2, b2, bM, NX, 1024, 4096, 0);
    ln_res_b<1,0><<<NX, blk, 0, stream>>>(xb, bM, lng + 3*1024, lnb + 3*1024, nullptr, out);
}

// Round 14
// 503.543 us; speedup vs baseline: 1.0313x; 1.0313x over previous
//
#include <hip/hip_runtime.h>
#include <math.h>

#define HIDN 1024
#define NHEADS 16
#define DHEAD 64
#define FFD 4096
#define LN_EPS 1e-6f
#define NEGV -1e9f

typedef __bf16 bf16_t;
typedef __bf16 bf16x8 __attribute__((ext_vector_type(8)));
typedef float f32x4 __attribute__((ext_vector_type(4)));
typedef unsigned short ushort8 __attribute__((ext_vector_type(8)));
typedef unsigned short ushort4v __attribute__((ext_vector_type(4)));

__device__ __forceinline__ unsigned short f2bf(float f) {
    unsigned u = __float_as_uint(f);
    return (unsigned short)((u + 0x7FFFu + ((u >> 16) & 1u)) >> 16);
}
__device__ __forceinline__ float bf2f(unsigned short u) {
    return __uint_as_float((unsigned)u << 16);
}
__device__ __forceinline__ void gld16(const void* g, void* l) {
    __builtin_amdgcn_global_load_lds(
        (const __attribute__((address_space(1))) void*)g,
        (__attribute__((address_space(3))) void*)l, 16, 0, 0);
}

// ---------------------------------------------------------------------------
// 128^2 bf16 MFMA GEMM body (proven rounds 6-8): BK=64, 4 waves, T2 swizzle,
// double-buffered LDS with issue-early staging. ~904 TF at these shapes
// (m97-structure ceiling; 4 deep-pipeline variants r9-r13 all <= this).
// Shared arrays are declared here; callers must have exactly ONE call site
// so only one 64 KB LDS allocation exists per kernel.
// ---------------------------------------------------------------------------
__device__ __forceinline__ void gemm128_body(
    const bf16_t* __restrict__ A, const bf16_t* __restrict__ W,
    const float* ba, const float* bb, const float* bc, const float* bd,
    unsigned short* __restrict__ Cb, int M, int N, int K,
    int m0, int n0, int relu)
{
    __shared__ __align__(16) bf16_t As[2][128 * 64];
    __shared__ __align__(16) bf16_t Bs[2][128 * 64];

    const int tid  = threadIdx.x;
    const int wid  = tid >> 6;
    const int lane = tid & 63;
    const int wm = (wid & 1) * 64;
    const int wn = (wid >> 1) * 64;

    const int sr = (wid << 3) + (lane >> 3);            // 0..31
    const int sk = (((lane & 7) ^ (lane >> 3)) * 8);
    const bf16_t* pa = A + (size_t)(m0 + sr) * K + sk;
    const bf16_t* pb = W + (size_t)(n0 + sr) * K + sk;
    const int lofs = (wid << 3) * 64;

    const int lr  = lane & 15;
    const int hi_ = lane >> 4;
    const int ch0 = ((hi_ + 0) ^ (lane & 7)) * 8;   // kk = 0
    const int ch1 = ((hi_ + 4) ^ (lane & 7)) * 8;   // kk = 32

    f32x4 acc[4][4];
    #pragma unroll
    for (int i = 0; i < 4; ++i)
        #pragma unroll
        for (int j = 0; j < 4; ++j) acc[i][j] = (f32x4){0.f, 0.f, 0.f, 0.f};

    auto stage = [&](int buf, int koff) {
        #pragma unroll
        for (int c = 0; c < 4; ++c) {
            gld16(pa + (size_t)c * 32 * K + koff, &As[buf][lofs + c * 32 * 64]);
            gld16(pb + (size_t)c * 32 * K + koff, &Bs[buf][lofs + c * 32 * 64]);
        }
    };
    auto compute = [&](int buf) {
        const bf16_t* fa = &As[buf][(wm + lr) * 64];
        const bf16_t* fb = &Bs[buf][(wn + lr) * 64];
        #pragma unroll
        for (int kk = 0; kk < 2; ++kk) {
            const int ch = kk ? ch1 : ch0;
            bf16x8 a[4], b[4];
            #pragma unroll
            for (int i = 0; i < 4; ++i) {
                a[i] = *(const bf16x8*)(fa + i * 16 * 64 + ch);
                b[i] = *(const bf16x8*)(fb + i * 16 * 64 + ch);
            }
            #pragma unroll
            for (int i = 0; i < 4; ++i)
                #pragma unroll
                for (int j = 0; j < 4; ++j)
                    acc[i][j] = __builtin_amdgcn_mfma_f32_16x16x32_bf16(
                        a[i], b[j], acc[i][j], 0, 0, 0);
        }
    };

    stage(0, 0);
    asm volatile("s_waitcnt vmcnt(0)" ::: "memory");
    __syncthreads();

    for (int k0 = 0; k0 < K; k0 += 128) {
        if (k0 + 64 < K) stage(1, k0 + 64);
        compute(0);
        asm volatile("s_waitcnt vmcnt(0)" ::: "memory");
        __syncthreads();
        if (k0 + 128 < K) stage(0, k0 + 128);
        compute(1);
        asm volatile("s_waitcnt vmcnt(0)" ::: "memory");
        __syncthreads();
    }

    const int seg = n0 >> 10;
    const float* bias = (seg == 0) ? ba : (seg == 1) ? bb : (seg == 2) ? bc : bd;
    const int nl = (n0 & 1023);
    const int er = wm + (lane >> 4) * 4;
    const int ec = wn + (lane & 15);
    float bv[4];
    #pragma unroll
    for (int j = 0; j < 4; ++j) bv[j] = bias[nl + ec + j * 16];
    #pragma unroll
    for (int i = 0; i < 4; ++i)
        #pragma unroll
        for (int j = 0; j < 4; ++j)
            #pragma unroll
            for (int r = 0; r < 4; ++r) {
                float v = acc[i][j][r] + bv[j];
                if (relu) v = fmaxf(v, 0.f);
                Cb[(size_t)(m0 + er + i * 16 + r) * N + (n0 + ec + j * 16)] = f2bf(v);
            }
}

template<int RELU>
__global__ __launch_bounds__(256)
void gemm_mfma(const bf16_t* __restrict__ A, const bf16_t* __restrict__ W,
               const float* __restrict__ ba, const float* __restrict__ bb,
               const float* __restrict__ bc, const float* __restrict__ bd,
               unsigned short* __restrict__ Cb, int M, int N, int K)
{
    gemm128_body(A, W, ba, bb, bc, bd, Cb, M, N, K,
                 blockIdx.x * 128, blockIdx.y * 128, RELU);
}

// ---------------------------------------------------------------------------
// Grouped dual GEMM: two independent problems (same K) in ONE dispatch.
// Problem 0: [M0,N0] (grid g0 = (M0/128)*(N0/128) blocks), problem 1 follows.
// Fills the chip during the small KV projection (alone it is 128-256 wg on
// 256 CUs) and removes one launch gap. Block-uniform select; single call
// site -> one 64 KB LDS allocation.
// ---------------------------------------------------------------------------
__global__ __launch_bounds__(256)
void gemm_dual(const bf16_t* __restrict__ A0, const bf16_t* __restrict__ W0,
               const float* b0, unsigned short* __restrict__ C0, int M0, int N0,
               const bf16_t* __restrict__ A1, const bf16_t* __restrict__ W1,
               const float* b1a, const float* b1b,
               unsigned short* __restrict__ C1, int M1, int N1, int K)
{
    const int g0 = (M0 >> 7) * (N0 >> 7);
    int id = blockIdx.x;
    const bf16_t* A; const bf16_t* W;
    const float *xa, *xb2, *xc, *xd;
    unsigned short* C; int M, N, m0, n0;
    if (id < g0) {
        const int gx = M0 >> 7;
        A = A0; W = W0; xa = b0; xb2 = b0; xc = b0; xd = b0;
        C = C0; M = M0; N = N0;
        m0 = (id % gx) * 128; n0 = (id / gx) * 128;
    } else {
        id -= g0;
        const int gx = M1 >> 7;
        A = A1; W = W1; xa = b1a; xb2 = b1b; xc = b1b; xd = b1b;
        C = C1; M = M1; N = N1;
        m0 = (id % gx) * 128; n0 = (id / gx) * 128;
    }
    gemm128_body(A, W, xa, xb2, xc, xd, C, M, N, K, m0, n0, 0);
}

// ---------------------------------------------------------------------------
// MFMA attention v2 (unchanged round 8): one block per (head,batch), 8 waves,
// K/V fetched once, swizzled LDS, async-STAGE split.
// ---------------------------------------------------------------------------
template<int HAS_MASK>
__global__ __launch_bounds__(512, 2)
void attn_mfma(const bf16_t* __restrict__ Q, const bf16_t* __restrict__ K,
               const bf16_t* __restrict__ V, int qstride, int kvstride,
               const int* __restrict__ mask,
               unsigned short* __restrict__ O, int Lk)
{
    __shared__ __align__(16) unsigned short Ks[64][72];    // [k][d] swz
    __shared__ __align__(16) unsigned short Vt[64][72];    // [d][k] swz
    __shared__ __align__(16) unsigned short Ps[128][72];   // [q][k] linear
    __shared__ int smask[64];

    const int tid  = threadIdx.x;
    const int wid  = tid >> 6;
    const int lane = tid & 63;
    const int lo   = lane & 15;
    const int hi   = lane >> 4;
    const int h    = blockIdx.x;
    const int b    = blockIdx.y;
    const int Lq   = 512;

    bf16x8 qf[4][2];
    #pragma unroll
    for (int s4 = 0; s4 < 4; ++s4) {
        const bf16_t* qp = Q + (size_t)(b*Lq + s4*128 + wid*16 + lo) * qstride
                             + h*DHEAD + hi*8;
        qf[s4][0] = *(const bf16x8*)qp;
        qf[s4][1] = *(const bf16x8*)(qp + 32);
    }

    float mrun[4][4], lrun[4][4];
    f32x4 Oc[4][4];
    #pragma unroll
    for (int s4 = 0; s4 < 4; ++s4)
        #pragma unroll
        for (int r = 0; r < 4; ++r) {
            mrun[s4][r] = -INFINITY; lrun[s4][r] = 0.f;
            Oc[s4][r] = (f32x4){0.f, 0.f, 0.f, 0.f};
        }

    ushort8 r0, r1;
    int mreg = 0;

    auto load_tile = [&](int k0) {
        if (tid < 256) {
            const int sr = tid >> 2, sc = (tid & 3) * 16;
            const unsigned short* kp = (const unsigned short*)
                (K + (size_t)(b*Lk + k0 + sr) * kvstride + h*DHEAD + sc);
            r0 = *(const ushort8*)kp;
            r1 = *(const ushort8*)(kp + 8);
        } else {
            const int t2 = tid - 256, sr = t2 >> 2, sc = (t2 & 3) * 16;
            const unsigned short* vp = (const unsigned short*)
                (V + (size_t)(b*Lk + k0 + sr) * kvstride + h*DHEAD + sc);
            r0 = *(const ushort8*)vp;
            r1 = *(const ushort8*)(vp + 8);
        }
        if (HAS_MASK && tid < 64) mreg = mask[b*Lk + k0 + tid];
    };
    auto store_tile = [&]() {
        if (tid < 256) {
            const int sr = tid >> 2, sc = (tid & 3) * 16;
            const int x = ((sr >> 3) & 7) << 3;
            *(ushort8*)&Ks[sr][sc ^ x]       = r0;
            *(ushort8*)&Ks[sr][(sc + 8) ^ x] = r1;
        } else {
            const int t2 = tid - 256, sr = t2 >> 2, sc = (t2 & 3) * 16;
            #pragma unroll
            for (int t = 0; t < 8; ++t) {
                const int d0 = sc + t, d1 = sc + 8 + t;
                Vt[d0][sr ^ (((d0 >> 3) & 7) << 3)] = r0[t];
                Vt[d1][sr ^ (((d1 >> 3) & 7) << 3)] = r1[t];
            }
        }
        if (HAS_MASK && tid < 64) smask[tid] = mreg;
    };

    load_tile(0);
    store_tile();
    __syncthreads();

    int k0 = 0;
    while (true) {
        const bool more = (k0 + 64 < Lk);
        if (more) load_tile(k0 + 64);

        #pragma unroll
        for (int s4 = 0; s4 < 4; ++s4) {
            f32x4 sv[4];
            #pragma unroll
            for (int j = 0; j < 4; ++j) sv[j] = (f32x4){0.f, 0.f, 0.f, 0.f};
            #pragma unroll
            for (int kk = 0; kk < 2; ++kk) {
                #pragma unroll
                for (int j = 0; j < 4; ++j) {
                    const int krow = j*16 + lo;
                    const int kcol = (kk*32 + hi*8) ^ (((krow >> 3) & 7) << 3);
                    bf16x8 bfrag = *(const bf16x8*)&Ks[krow][kcol];
                    sv[j] = __builtin_amdgcn_mfma_f32_16x16x32_bf16(
                        qf[s4][kk], bfrag, sv[j], 0, 0, 0);
                }
            }
            #pragma unroll
            for (int j = 0; j < 4; ++j) {
                bool msk = HAS_MASK ? (smask[j*16 + lo] != 0) : false;
                #pragma unroll
                for (int r = 0; r < 4; ++r) {
                    float x = sv[j][r] * 0.125f;
                    sv[j][r] = msk ? NEGV : x;
                }
            }
            #pragma unroll
            for (int r = 0; r < 4; ++r) {
                float tm = fmaxf(fmaxf(sv[0][r], sv[1][r]), fmaxf(sv[2][r], sv[3][r]));
                #pragma unroll
                for (int m = 1; m < 16; m <<= 1) tm = fmaxf(tm, __shfl_xor(tm, m));
                float mnew = fmaxf(mrun[s4][r], tm);
                float f = __expf(mrun[s4][r] - mnew);
                float ps = 0.f;
                #pragma unroll
                for (int j = 0; j < 4; ++j) {
                    float p = __expf(sv[j][r] - mnew);
                    sv[j][r] = p;
                    ps += p;
                }
                #pragma unroll
                for (int m = 1; m < 16; m <<= 1) ps += __shfl_xor(ps, m);
                lrun[s4][r] = lrun[s4][r] * f + ps;
                mrun[s4][r] = mnew;
                #pragma unroll
                for (int n = 0; n < 4; ++n) Oc[s4][n][r] *= f;
                #pragma unroll
                for (int j = 0; j < 4; ++j)
                    Ps[wid*16 + hi*4 + r][j*16 + lo] = f2bf(sv[j][r]);
            }
            #pragma unroll
            for (int kk = 0; kk < 2; ++kk) {
                bf16x8 pa = *(const bf16x8*)&Ps[wid*16 + lo][kk*32 + hi*8];
                #pragma unroll
                for (int n = 0; n < 4; ++n) {
                    const int vrow = n*16 + lo;
                    const int vcol = (kk*32 + hi*8) ^ (((vrow >> 3) & 7) << 3);
                    bf16x8 vf = *(const bf16x8*)&Vt[vrow][vcol];
                    Oc[s4][n] = __builtin_amdgcn_mfma_f32_16x16x32_bf16(
                        pa, vf, Oc[s4][n], 0, 0, 0);
                }
            }
        }

        if (!more) break;
        __syncthreads();
        store_tile();
        __syncthreads();
        k0 += 64;
    }

    #pragma unroll
    for (int s4 = 0; s4 < 4; ++s4)
        #pragma unroll
        for (int r = 0; r < 4; ++r) {
            float inv = 1.f / lrun[s4][r];
            const size_t row = (size_t)(b*Lq + s4*128 + wid*16 + hi*4 + r) * HIDN
                             + h*DHEAD;
            #pragma unroll
            for (int n = 0; n < 4; ++n)
                O[row + n*16 + lo] = f2bf(Oc[s4][n][r] * inv);
        }
}

// ---------------------------------------------------------------------------
// LayerNorm(X + R): X,R bf16; stats fp32; write bf16 (in-place ok) and/or f32.
// ---------------------------------------------------------------------------
template<int WF32, int WBF>
__global__ __launch_bounds__(256)
void ln_res_b(const unsigned short* __restrict__ X, const unsigned short* __restrict__ R,
              const float* __restrict__ G, const float* __restrict__ Bv,
              unsigned short* __restrict__ OutB, float* __restrict__ OutF)
{
    const int row = blockIdx.x;
    const int tid = threadIdx.x;
    const size_t base = (size_t)row * HIDN + tid * 4;
    ushort4v xv = *(const ushort4v*)(X + base);
    ushort4v rv = *(const ushort4v*)(R + base);
    float y[4];
    #pragma unroll
    for (int t = 0; t < 4; ++t) y[t] = bf2f(xv[t]) + bf2f(rv[t]);
    float s1 = y[0] + y[1] + y[2] + y[3];
    float s2 = y[0]*y[0] + y[1]*y[1] + y[2]*y[2] + y[3]*y[3];
    #pragma unroll
    for (int m = 1; m < 64; m <<= 1) {
        s1 += __shfl_xor(s1, m);
        s2 += __shfl_xor(s2, m);
    }
    __shared__ float red1[4], red2[4];
    const int wave = tid >> 6, lane = tid & 63;
    if (lane == 0) { red1[wave] = s1; red2[wave] = s2; }
    __syncthreads();
    s1 = red1[0] + red1[1] + red1[2] + red1[3];
    s2 = red2[0] + red2[1] + red2[2] + red2[3];
    const float mean = s1 * (1.f / HIDN);
    const float var  = s2 * (1.f / HIDN) - mean * mean;
    const float inv  = rsqrtf(var + LN_EPS);
    float4 gv = *(const float4*)(G + tid*4);
    float4 bv = *(const float4*)(Bv + tid*4);
    float o[4];
    o[0] = gv.x * (y[0]-mean) * inv + bv.x;
    o[1] = gv.y * (y[1]-mean) * inv + bv.y;
    o[2] = gv.z * (y[2]-mean) * inv + bv.z;
    o[3] = gv.w * (y[3]-mean) * inv + bv.w;
    if (WBF) {
        ushort4v ob;
        #pragma unroll
        for (int t = 0; t < 4; ++t) ob[t] = f2bf(o[t]);
        *(ushort4v*)(OutB + base) = ob;
    }
    if (WF32) {
        float4 of = {o[0], o[1], o[2], o[3]};
        *(float4*)(OutF + base) = of;
    }
}

// ---------------------------------------------------------------------------
// One-shot fp32 -> bf16 conversion of 1Mi-element units (weights + acts).
// ---------------------------------------------------------------------------
struct CvtArgs {
    const float* src[32];
    unsigned short* dst[32];
};

__global__ __launch_bounds__(256)
void cvt_units(CvtArgs args)
{
    const float* s = args.src[blockIdx.y];
    unsigned short* d = args.dst[blockIdx.y];
    const int i = blockIdx.x * 256 + threadIdx.x;   // 0..131071
    const float4* p = (const float4*)s + (size_t)i * 2;
    float4 a = p[0], b = p[1];
    ushort8 o;
    o[0] = f2bf(a.x); o[1] = f2bf(a.y); o[2] = f2bf(a.z); o[3] = f2bf(a.w);
    o[4] = f2bf(b.x); o[5] = f2bf(b.y); o[6] = f2bf(b.z); o[7] = f2bf(b.w);
    ((ushort8*)d)[i] = o;
}

// ---------------------------------------------------------------------------
extern "C" void kernel_launch(void* const* d_in, const int* in_sizes, int n_in,
                              void* d_out, int out_size, void* d_ws, size_t ws_size,
                              hipStream_t stream)
{
    const float* img   = (const float*)d_in[0];
    const float* ques  = (const float*)d_in[1];
    const float* kg    = (const float*)d_in[2];
    const int*   qmask = (const int*)d_in[3];
    const int*   kmask = (const int*)d_in[4];
    const float* qw = (const float*)d_in[5];
    const float* qb = (const float*)d_in[6];
    const float* kw = (const float*)d_in[7];
    const float* kb = (const float*)d_in[8];
    const float* vw = (const float*)d_in[9];
    const float* vb = (const float*)d_in[10];
    const float* ow = (const float*)d_in[11];
    const float* ob = (const float*)d_in[12];
    const float* w1 = (const float*)d_in[13];
    const float* b1 = (const float*)d_in[14];
    const float* w2 = (const float*)d_in[15];
    const float* b2 = (const float*)d_in[16];
    const float* lng = (const float*)d_in[17];
    const float* lnb = (const float*)d_in[18];
    float* out = (float*)d_out;

    const int B = 16;
    const int NX = B * 512;                    // 8192 rows
    const size_t WSTEP = (size_t)1024 * 1024;
    const size_t MB = (size_t)1 << 20;
    const size_t MELEM = (size_t)1024 * 1024;

    char* wsb = (char*)d_ws;
    unsigned short* xb    = (unsigned short*)(wsb);            // 16 MB
    unsigned short* bM    = (unsigned short*)(wsb + 16*MB);    // 16 MB
    unsigned short* bOb   = (unsigned short*)(wsb + 32*MB);    // 16 MB
    unsigned short* quesb = (unsigned short*)(wsb + 48*MB);    //  2 MB
    unsigned short* kgb   = (unsigned short*)(wsb + 50*MB);    //  4 MB
    unsigned short* wa    = (unsigned short*)(wsb + 56*MB);    // 40 MB weight arena
    unsigned short* bQKV  = (unsigned short*)(wsb + 96*MB);    // 48 MB
    unsigned short* bKV   = (unsigned short*)(wsb + 144*MB);   //  8 MB
    unsigned short* hb    = (unsigned short*)(wsb + 96*MB);    // 64 MB, overlays bQKV/bKV

    CvtArgs ca;
    int u = 0;
    auto addu = [&](const float* src, int melems, unsigned short* dst) {
        for (int i = 0; i < melems; ++i) {
            ca.src[u] = src + (size_t)i * MELEM;
            ca.dst[u] = dst + (size_t)i * MELEM;
            ++u;
        }
    };
    addu(qw + 0*WSTEP, 1, wa + 0*MELEM);
    addu(kw + 0*WSTEP, 1, wa + 1*MELEM);
    addu(vw + 0*WSTEP, 1, wa + 2*MELEM);
    addu(qw + 1*WSTEP, 1, wa + 3*MELEM);
    addu(kw + 1*WSTEP, 1, wa + 4*MELEM);
    addu(vw + 1*WSTEP, 1, wa + 5*MELEM);
    addu(qw + 2*WSTEP, 1, wa + 6*MELEM);
    addu(kw + 2*WSTEP, 1, wa + 7*MELEM);
    addu(vw + 2*WSTEP, 1, wa + 8*MELEM);
    addu(ow + 0*WSTEP, 1, wa + 9*MELEM);
    addu(ow + 1*WSTEP, 1, wa + 10*MELEM);
    addu(ow + 2*WSTEP, 1, wa + 11*MELEM);
    addu(w1, 4, wa + 12*MELEM);
    addu(w2, 4, wa + 16*MELEM);
    addu(img,  8, xb);
    addu(ques, 1, quesb);
    addu(kg,   2, kgb);

    dim3 blk(256);
    cvt_units<<<dim3(512, u), blk, 0, stream>>>(ca);

    auto gemm = [&](const unsigned short* A, const unsigned short* W,
                    const float* ba, const float* bb_, const float* bc, const float* bd,
                    unsigned short* C, int M, int N, int K, int relu) {
        dim3 grid(M / 128, N / 128);
        if (relu) gemm_mfma<1><<<grid, blk, 0, stream>>>(
            (const bf16_t*)A, (const bf16_t*)W, ba, bb_, bc, bd, C, M, N, K);
        else      gemm_mfma<0><<<grid, blk, 0, stream>>>(
            (const bf16_t*)A, (const bf16_t*)W, ba, bb_, bc, bd, C, M, N, K);
    };

    const unsigned short* Akv[3] = {xb, quesb, kgb};
    const int Mkv[3] = {NX, B * 64, B * 128};
    const int Lk[3]  = {512, 64, 128};

    dim3 ablk(512);
    dim3 agrid(NHEADS, B);

    for (int t = 0; t < 3; ++t) {
        if (t == 0) {
            gemm(xb, wa + 0*MELEM, qb + 0, kb + 0, vb + 0, vb + 0,
                 bQKV, NX, 3072, 1024, 0);
            attn_mfma<0><<<agrid, ablk, 0, stream>>>(
                (const bf16_t*)bQKV, (const bf16_t*)bQKV + 1024, (const bf16_t*)bQKV + 2048,
                3072, 3072, nullptr, bOb, Lk[t]);
        } else {
            // grouped: Q projection (M=8192,N=1024) + KV projection in ONE dispatch
            const int M1 = Mkv[t];
            const int g0 = (NX / 128) * (1024 / 128);        // 512
            const int g1 = (M1 / 128) * (2048 / 128);        // 128 or 256
            gemm_dual<<<dim3(g0 + g1), blk, 0, stream>>>(
                (const bf16_t*)xb, (const bf16_t*)(wa + (t == 1 ? 3 : 6)*MELEM),
                qb + t*1024, bQKV, NX, 1024,
                (const bf16_t*)Akv[t], (const bf16_t*)(wa + (t == 1 ? 4 : 7)*MELEM),
                kb + t*1024, vb + t*1024, bKV, M1, 2048, 1024);
            attn_mfma<1><<<agrid, ablk, 0, stream>>>(
                (const bf16_t*)bQKV, (const bf16_t*)bKV, (const bf16_t*)bKV + 1024,
                1024, 2048, (t == 1 ? qmask : kmask), bOb, Lk[t]);
        }
        gemm(bOb, wa + (9 + t)*MELEM,
             ob + t*1024, ob + t*1024, ob + t*1024, ob + t*1024,
             bM, NX, 1024, 1024, 0);
        ln_res_b<0,1><<<NX, blk, 0, stream>>>(xb, bM, lng + t*1024, lnb + t*1024, xb, nullptr);
    }

    // FFN
    gemm(xb, wa + 12*MELEM, b1, b1 + 1024, b1 + 2048, b1 + 3072, hb, NX, FFD, 1024, 1);
    gemm(hb, wa + 16*MELEM, b2, b2, b2, b2, bM, NX, 1024, 4096, 0);
    ln_res_b<1,0><<<NX, blk, 0, stream>>>(xb, bM, lng + 3*1024, lnb + 3*1024, nullptr, out);
}

// Round 15
// 496.112 us; speedup vs baseline: 1.0467x; 1.0150x over previous
//
#include <hip/hip_runtime.h>
#include <math.h>

#define HIDN 1024
#define NHEADS 16
#define DHEAD 64
#define FFD 4096
#define LN_EPS 1e-6f
#define NEGV -1e9f

typedef __bf16 bf16_t;
typedef __bf16 bf16x8 __attribute__((ext_vector_type(8)));
typedef float f32x4 __attribute__((ext_vector_type(4)));
typedef unsigned short ushort8 __attribute__((ext_vector_type(8)));
typedef unsigned short ushort4v __attribute__((ext_vector_type(4)));

__device__ __forceinline__ unsigned short f2bf(float f) {
    unsigned u = __float_as_uint(f);
    return (unsigned short)((u + 0x7FFFu + ((u >> 16) & 1u)) >> 16);
}
__device__ __forceinline__ float bf2f(unsigned short u) {
    return __uint_as_float((unsigned)u << 16);
}
__device__ __forceinline__ void gld16(const void* g, void* l) {
    __builtin_amdgcn_global_load_lds(
        (const __attribute__((address_space(1))) void*)g,
        (__attribute__((address_space(3))) void*)l, 16, 0, 0);
}

// ---------------------------------------------------------------------------
// 128^2 bf16 MFMA GEMM body (proven rounds 6-8): BK=64, 4 waves, T2 swizzle,
// double-buffered LDS with issue-early staging. ~904 TF at these shapes —
// the m97-structure ceiling (5 deep-pipeline variants r9-r13 all <= this).
// ONE call site per kernel (single 64 KB LDS allocation).
// ---------------------------------------------------------------------------
__device__ __forceinline__ void gemm128_body(
    const bf16_t* __restrict__ A, const bf16_t* __restrict__ W,
    const float* ba, const float* bb, const float* bc, const float* bd,
    unsigned short* __restrict__ Cb, int M, int N, int K,
    int m0, int n0, int relu)
{
    __shared__ __align__(16) bf16_t As[2][128 * 64];
    __shared__ __align__(16) bf16_t Bs[2][128 * 64];

    const int tid  = threadIdx.x;
    const int wid  = tid >> 6;
    const int lane = tid & 63;
    const int wm = (wid & 1) * 64;
    const int wn = (wid >> 1) * 64;

    const int sr = (wid << 3) + (lane >> 3);            // 0..31
    const int sk = (((lane & 7) ^ (lane >> 3)) * 8);
    const bf16_t* pa = A + (size_t)(m0 + sr) * K + sk;
    const bf16_t* pb = W + (size_t)(n0 + sr) * K + sk;
    const int lofs = (wid << 3) * 64;

    const int lr  = lane & 15;
    const int hi_ = lane >> 4;
    const int ch0 = ((hi_ + 0) ^ (lane & 7)) * 8;   // kk = 0
    const int ch1 = ((hi_ + 4) ^ (lane & 7)) * 8;   // kk = 32

    f32x4 acc[4][4];
    #pragma unroll
    for (int i = 0; i < 4; ++i)
        #pragma unroll
        for (int j = 0; j < 4; ++j) acc[i][j] = (f32x4){0.f, 0.f, 0.f, 0.f};

    auto stage = [&](int buf, int koff) {
        #pragma unroll
        for (int c = 0; c < 4; ++c) {
            gld16(pa + (size_t)c * 32 * K + koff, &As[buf][lofs + c * 32 * 64]);
            gld16(pb + (size_t)c * 32 * K + koff, &Bs[buf][lofs + c * 32 * 64]);
        }
    };
    auto compute = [&](int buf) {
        const bf16_t* fa = &As[buf][(wm + lr) * 64];
        const bf16_t* fb = &Bs[buf][(wn + lr) * 64];
        #pragma unroll
        for (int kk = 0; kk < 2; ++kk) {
            const int ch = kk ? ch1 : ch0;
            bf16x8 a[4], b[4];
            #pragma unroll
            for (int i = 0; i < 4; ++i) {
                a[i] = *(const bf16x8*)(fa + i * 16 * 64 + ch);
                b[i] = *(const bf16x8*)(fb + i * 16 * 64 + ch);
            }
            #pragma unroll
            for (int i = 0; i < 4; ++i)
                #pragma unroll
                for (int j = 0; j < 4; ++j)
                    acc[i][j] = __builtin_amdgcn_mfma_f32_16x16x32_bf16(
                        a[i], b[j], acc[i][j], 0, 0, 0);
        }
    };

    stage(0, 0);
    asm volatile("s_waitcnt vmcnt(0)" ::: "memory");
    __syncthreads();

    for (int k0 = 0; k0 < K; k0 += 128) {
        if (k0 + 64 < K) stage(1, k0 + 64);
        compute(0);
        asm volatile("s_waitcnt vmcnt(0)" ::: "memory");
        __syncthreads();
        if (k0 + 128 < K) stage(0, k0 + 128);
        compute(1);
        asm volatile("s_waitcnt vmcnt(0)" ::: "memory");
        __syncthreads();
    }

    const int seg = n0 >> 10;
    const float* bias = (seg == 0) ? ba : (seg == 1) ? bb : (seg == 2) ? bc : bd;
    const int nl = (n0 & 1023);
    const int er = wm + (lane >> 4) * 4;
    const int ec = wn + (lane & 15);
    float bv[4];
    #pragma unroll
    for (int j = 0; j < 4; ++j) bv[j] = bias[nl + ec + j * 16];
    #pragma unroll
    for (int i = 0; i < 4; ++i)
        #pragma unroll
        for (int j = 0; j < 4; ++j)
            #pragma unroll
            for (int r = 0; r < 4; ++r) {
                float v = acc[i][j][r] + bv[j];
                if (relu) v = fmaxf(v, 0.f);
                Cb[(size_t)(m0 + er + i * 16 + r) * N + (n0 + ec + j * 16)] = f2bf(v);
            }
}

template<int RELU>
__global__ __launch_bounds__(256)
void gemm_mfma(const bf16_t* __restrict__ A, const bf16_t* __restrict__ W,
               const float* __restrict__ ba, const float* __restrict__ bb,
               const float* __restrict__ bc, const float* __restrict__ bd,
               unsigned short* __restrict__ Cb, int M, int N, int K)
{
    gemm128_body(A, W, ba, bb, bc, bd, Cb, M, N, K,
                 blockIdx.x * 128, blockIdx.y * 128, RELU);
}

// ---------------------------------------------------------------------------
// Grouped triple GEMM: three independent problems (same K) in ONE dispatch.
// P0 = fused QKV (t=0), P1 = KV (t=1, input ques), P2 = KV (t=2, input kg).
// The small KV problems ride P0's partial pass instead of trailing their
// own dispatches. Block-uniform select; single call site -> one 64 KB LDS.
// ---------------------------------------------------------------------------
__global__ __launch_bounds__(256)
void gemm_triple(const bf16_t* __restrict__ A0, const bf16_t* __restrict__ W0,
                 const float* b0a, const float* b0b, const float* b0c,
                 unsigned short* __restrict__ C0, int M0, int N0,
                 const bf16_t* __restrict__ A1, const bf16_t* __restrict__ W1,
                 const float* b1a, const float* b1b,
                 unsigned short* __restrict__ C1, int M1, int N1,
                 const bf16_t* __restrict__ A2, const bf16_t* __restrict__ W2,
                 const float* b2a, const float* b2b,
                 unsigned short* __restrict__ C2, int M2, int N2, int K)
{
    const int g0 = (M0 >> 7) * (N0 >> 7);
    const int g1 = (M1 >> 7) * (N1 >> 7);
    int id = blockIdx.x;
    const bf16_t* A; const bf16_t* W;
    const float *xa, *xb2, *xc, *xd;
    unsigned short* C; int M, N, m0, n0;
    if (id < g0) {
        const int gx = M0 >> 7;
        A = A0; W = W0; xa = b0a; xb2 = b0b; xc = b0c; xd = b0c;
        C = C0; M = M0; N = N0;
        m0 = (id % gx) * 128; n0 = (id / gx) * 128;
    } else if (id < g0 + g1) {
        id -= g0;
        const int gx = M1 >> 7;
        A = A1; W = W1; xa = b1a; xb2 = b1b; xc = b1b; xd = b1b;
        C = C1; M = M1; N = N1;
        m0 = (id % gx) * 128; n0 = (id / gx) * 128;
    } else {
        id -= g0 + g1;
        const int gx = M2 >> 7;
        A = A2; W = W2; xa = b2a; xb2 = b2b; xc = b2b; xd = b2b;
        C = C2; M = M2; N = N2;
        m0 = (id % gx) * 128; n0 = (id / gx) * 128;
    }
    gemm128_body(A, W, xa, xb2, xc, xd, C, M, N, K, m0, n0, 0);
}

// ---------------------------------------------------------------------------
// MFMA attention v3: grid (head, batch, 2) = 512 blocks (fills the chip at
// 2 blocks/CU; v2's 256 blocks left half the CUs idle). Each block owns 2
// strips of 128 q-rows (blockIdx.z selects which half). K/V staged per block
// (2x reads, L2-absorbed). Same per-row math/order as v2 -> bit-identical.
// ---------------------------------------------------------------------------
template<int HAS_MASK>
__global__ __launch_bounds__(512, 2)
void attn_mfma(const bf16_t* __restrict__ Q, const bf16_t* __restrict__ K,
               const bf16_t* __restrict__ V, int qstride, int kvstride,
               const int* __restrict__ mask,
               unsigned short* __restrict__ O, int Lk)
{
    __shared__ __align__(16) unsigned short Ks[64][72];    // [k][d] swz
    __shared__ __align__(16) unsigned short Vt[64][72];    // [d][k] swz
    __shared__ __align__(16) unsigned short Ps[128][72];   // [q][k] linear
    __shared__ int smask[64];

    const int tid  = threadIdx.x;
    const int wid  = tid >> 6;
    const int lane = tid & 63;
    const int lo   = lane & 15;
    const int hi   = lane >> 4;
    const int h    = blockIdx.x;
    const int b    = blockIdx.y;
    const int z    = blockIdx.z;     // q-half: strips z*2, z*2+1
    const int Lq   = 512;

    bf16x8 qf[2][2];
    #pragma unroll
    for (int s4 = 0; s4 < 2; ++s4) {
        const bf16_t* qp = Q + (size_t)(b*Lq + (z*2 + s4)*128 + wid*16 + lo) * qstride
                             + h*DHEAD + hi*8;
        qf[s4][0] = *(const bf16x8*)qp;
        qf[s4][1] = *(const bf16x8*)(qp + 32);
    }

    float mrun[2][4], lrun[2][4];
    f32x4 Oc[2][4];
    #pragma unroll
    for (int s4 = 0; s4 < 2; ++s4)
        #pragma unroll
        for (int r = 0; r < 4; ++r) {
            mrun[s4][r] = -INFINITY; lrun[s4][r] = 0.f;
            Oc[s4][r] = (f32x4){0.f, 0.f, 0.f, 0.f};
        }

    ushort8 r0, r1;
    int mreg = 0;

    auto load_tile = [&](int k0) {
        if (tid < 256) {
            const int sr = tid >> 2, sc = (tid & 3) * 16;
            const unsigned short* kp = (const unsigned short*)
                (K + (size_t)(b*Lk + k0 + sr) * kvstride + h*DHEAD + sc);
            r0 = *(const ushort8*)kp;
            r1 = *(const ushort8*)(kp + 8);
        } else {
            const int t2 = tid - 256, sr = t2 >> 2, sc = (t2 & 3) * 16;
            const unsigned short* vp = (const unsigned short*)
                (V + (size_t)(b*Lk + k0 + sr) * kvstride + h*DHEAD + sc);
            r0 = *(const ushort8*)vp;
            r1 = *(const ushort8*)(vp + 8);
        }
        if (HAS_MASK && tid < 64) mreg = mask[b*Lk + k0 + tid];
    };
    auto store_tile = [&]() {
        if (tid < 256) {
            const int sr = tid >> 2, sc = (tid & 3) * 16;
            const int x = ((sr >> 3) & 7) << 3;
            *(ushort8*)&Ks[sr][sc ^ x]       = r0;
            *(ushort8*)&Ks[sr][(sc + 8) ^ x] = r1;
        } else {
            const int t2 = tid - 256, sr = t2 >> 2, sc = (t2 & 3) * 16;
            #pragma unroll
            for (int t = 0; t < 8; ++t) {
                const int d0 = sc + t, d1 = sc + 8 + t;
                Vt[d0][sr ^ (((d0 >> 3) & 7) << 3)] = r0[t];
                Vt[d1][sr ^ (((d1 >> 3) & 7) << 3)] = r1[t];
            }
        }
        if (HAS_MASK && tid < 64) smask[tid] = mreg;
    };

    load_tile(0);
    store_tile();
    __syncthreads();

    int k0 = 0;
    while (true) {
        const bool more = (k0 + 64 < Lk);
        if (more) load_tile(k0 + 64);

        #pragma unroll
        for (int s4 = 0; s4 < 2; ++s4) {
            f32x4 sv[4];
            #pragma unroll
            for (int j = 0; j < 4; ++j) sv[j] = (f32x4){0.f, 0.f, 0.f, 0.f};
            #pragma unroll
            for (int kk = 0; kk < 2; ++kk) {
                #pragma unroll
                for (int j = 0; j < 4; ++j) {
                    const int krow = j*16 + lo;
                    const int kcol = (kk*32 + hi*8) ^ (((krow >> 3) & 7) << 3);
                    bf16x8 bfrag = *(const bf16x8*)&Ks[krow][kcol];
                    sv[j] = __builtin_amdgcn_mfma_f32_16x16x32_bf16(
                        qf[s4][kk], bfrag, sv[j], 0, 0, 0);
                }
            }
            #pragma unroll
            for (int j = 0; j < 4; ++j) {
                bool msk = HAS_MASK ? (smask[j*16 + lo] != 0) : false;
                #pragma unroll
                for (int r = 0; r < 4; ++r) {
                    float x = sv[j][r] * 0.125f;
                    sv[j][r] = msk ? NEGV : x;
                }
            }
            #pragma unroll
            for (int r = 0; r < 4; ++r) {
                float tm = fmaxf(fmaxf(sv[0][r], sv[1][r]), fmaxf(sv[2][r], sv[3][r]));
                #pragma unroll
                for (int m = 1; m < 16; m <<= 1) tm = fmaxf(tm, __shfl_xor(tm, m));
                float mnew = fmaxf(mrun[s4][r], tm);
                float f = __expf(mrun[s4][r] - mnew);
                float ps = 0.f;
                #pragma unroll
                for (int j = 0; j < 4; ++j) {
                    float p = __expf(sv[j][r] - mnew);
                    sv[j][r] = p;
                    ps += p;
                }
                #pragma unroll
                for (int m = 1; m < 16; m <<= 1) ps += __shfl_xor(ps, m);
                lrun[s4][r] = lrun[s4][r] * f + ps;
                mrun[s4][r] = mnew;
                #pragma unroll
                for (int n = 0; n < 4; ++n) Oc[s4][n][r] *= f;
                #pragma unroll
                for (int j = 0; j < 4; ++j)
                    Ps[wid*16 + hi*4 + r][j*16 + lo] = f2bf(sv[j][r]);
            }
            #pragma unroll
            for (int kk = 0; kk < 2; ++kk) {
                bf16x8 pa = *(const bf16x8*)&Ps[wid*16 + lo][kk*32 + hi*8];
                #pragma unroll
                for (int n = 0; n < 4; ++n) {
                    const int vrow = n*16 + lo;
                    const int vcol = (kk*32 + hi*8) ^ (((vrow >> 3) & 7) << 3);
                    bf16x8 vf = *(const bf16x8*)&Vt[vrow][vcol];
                    Oc[s4][n] = __builtin_amdgcn_mfma_f32_16x16x32_bf16(
                        pa, vf, Oc[s4][n], 0, 0, 0);
                }
            }
        }

        if (!more) break;
        __syncthreads();
        store_tile();
        __syncthreads();
        k0 += 64;
    }

    #pragma unroll
    for (int s4 = 0; s4 < 2; ++s4)
        #pragma unroll
        for (int r = 0; r < 4; ++r) {
            float inv = 1.f / lrun[s4][r];
            const size_t row = (size_t)(b*Lq + (z*2 + s4)*128 + wid*16 + hi*4 + r) * HIDN
                             + h*DHEAD;
            #pragma unroll
            for (int n = 0; n < 4; ++n)
                O[row + n*16 + lo] = f2bf(Oc[s4][n][r] * inv);
        }
}

// ---------------------------------------------------------------------------
// LayerNorm(X + R): X,R bf16; stats fp32; write bf16 (in-place ok) and/or f32.
// ---------------------------------------------------------------------------
template<int WF32, int WBF>
__global__ __launch_bounds__(256)
void ln_res_b(const unsigned short* __restrict__ X, const unsigned short* __restrict__ R,
              const float* __restrict__ G, const float* __restrict__ Bv,
              unsigned short* __restrict__ OutB, float* __restrict__ OutF)
{
    const int row = blockIdx.x;
    const int tid = threadIdx.x;
    const size_t base = (size_t)row * HIDN + tid * 4;
    ushort4v xv = *(const ushort4v*)(X + base);
    ushort4v rv = *(const ushort4v*)(R + base);
    float y[4];
    #pragma unroll
    for (int t = 0; t < 4; ++t) y[t] = bf2f(xv[t]) + bf2f(rv[t]);
    float s1 = y[0] + y[1] + y[2] + y[3];
    float s2 = y[0]*y[0] + y[1]*y[1] + y[2]*y[2] + y[3]*y[3];
    #pragma unroll
    for (int m = 1; m < 64; m <<= 1) {
        s1 += __shfl_xor(s1, m);
        s2 += __shfl_xor(s2, m);
    }
    __shared__ float red1[4], red2[4];
    const int wave = tid >> 6, lane = tid & 63;
    if (lane == 0) { red1[wave] = s1; red2[wave] = s2; }
    __syncthreads();
    s1 = red1[0] + red1[1] + red1[2] + red1[3];
    s2 = red2[0] + red2[1] + red2[2] + red2[3];
    const float mean = s1 * (1.f / HIDN);
    const float var  = s2 * (1.f / HIDN) - mean * mean;
    const float inv  = rsqrtf(var + LN_EPS);
    float4 gv = *(const float4*)(G + tid*4);
    float4 bv = *(const float4*)(Bv + tid*4);
    float o[4];
    o[0] = gv.x * (y[0]-mean) * inv + bv.x;
    o[1] = gv.y * (y[1]-mean) * inv + bv.y;
    o[2] = gv.z * (y[2]-mean) * inv + bv.z;
    o[3] = gv.w * (y[3]-mean) * inv + bv.w;
    if (WBF) {
        ushort4v ob;
        #pragma unroll
        for (int t = 0; t < 4; ++t) ob[t] = f2bf(o[t]);
        *(ushort4v*)(OutB + base) = ob;
    }
    if (WF32) {
        float4 of = {o[0], o[1], o[2], o[3]};
        *(float4*)(OutF + base) = of;
    }
}

// ---------------------------------------------------------------------------
// One-shot fp32 -> bf16 conversion of 1Mi-element units (weights + acts).
// ---------------------------------------------------------------------------
struct CvtArgs {
    const float* src[32];
    unsigned short* dst[32];
};

__global__ __launch_bounds__(256)
void cvt_units(CvtArgs args)
{
    const float* s = args.src[blockIdx.y];
    unsigned short* d = args.dst[blockIdx.y];
    const int i = blockIdx.x * 256 + threadIdx.x;   // 0..131071
    const float4* p = (const float4*)s + (size_t)i * 2;
    float4 a = p[0], b = p[1];
    ushort8 o;
    o[0] = f2bf(a.x); o[1] = f2bf(a.y); o[2] = f2bf(a.z); o[3] = f2bf(a.w);
    o[4] = f2bf(b.x); o[5] = f2bf(b.y); o[6] = f2bf(b.z); o[7] = f2bf(b.w);
    ((ushort8*)d)[i] = o;
}

// ---------------------------------------------------------------------------
extern "C" void kernel_launch(void* const* d_in, const int* in_sizes, int n_in,
                              void* d_out, int out_size, void* d_ws, size_t ws_size,
                              hipStream_t stream)
{
    const float* img   = (const float*)d_in[0];
    const float* ques  = (const float*)d_in[1];
    const float* kg    = (const float*)d_in[2];
    const int*   qmask = (const int*)d_in[3];
    const int*   kmask = (const int*)d_in[4];
    const float* qw = (const float*)d_in[5];
    const float* qb = (const float*)d_in[6];
    const float* kw = (const float*)d_in[7];
    const float* kb = (const float*)d_in[8];
    const float* vw = (const float*)d_in[9];
    const float* vb = (const float*)d_in[10];
    const float* ow = (const float*)d_in[11];
    const float* ob = (const float*)d_in[12];
    const float* w1 = (const float*)d_in[13];
    const float* b1 = (const float*)d_in[14];
    const float* w2 = (const float*)d_in[15];
    const float* b2 = (const float*)d_in[16];
    const float* lng = (const float*)d_in[17];
    const float* lnb = (const float*)d_in[18];
    float* out = (float*)d_out;

    const int B = 16;
    const int NX = B * 512;                    // 8192 rows
    const size_t WSTEP = (size_t)1024 * 1024;
    const size_t MB = (size_t)1 << 20;
    const size_t MELEM = (size_t)1024 * 1024;

    char* wsb = (char*)d_ws;
    unsigned short* xb    = (unsigned short*)(wsb);            // 16 MB
    unsigned short* bM    = (unsigned short*)(wsb + 16*MB);    // 16 MB
    unsigned short* bOb   = (unsigned short*)(wsb + 32*MB);    // 16 MB
    unsigned short* quesb = (unsigned short*)(wsb + 48*MB);    //  2 MB
    unsigned short* kgb   = (unsigned short*)(wsb + 50*MB);    //  4 MB
    unsigned short* wa    = (unsigned short*)(wsb + 56*MB);    // 40 MB weight arena
    unsigned short* bQKV  = (unsigned short*)(wsb + 96*MB);    // 48 MB (t0 QKV / t1,t2 Q)
    unsigned short* bKV1  = (unsigned short*)(wsb + 144*MB);   //  4 MB (t1 KV)
    unsigned short* bKV2  = (unsigned short*)(wsb + 148*MB);   //  8 MB (t2 KV)
    unsigned short* hb    = (unsigned short*)(wsb + 96*MB);    // 64 MB, overlays bQKV/bKV* (dead in FFN)

    CvtArgs ca;
    int u = 0;
    auto addu = [&](const float* src, int melems, unsigned short* dst) {
        for (int i = 0; i < melems; ++i) {
            ca.src[u] = src + (size_t)i * MELEM;
            ca.dst[u] = dst + (size_t)i * MELEM;
            ++u;
        }
    };
    addu(qw + 0*WSTEP, 1, wa + 0*MELEM);
    addu(kw + 0*WSTEP, 1, wa + 1*MELEM);
    addu(vw + 0*WSTEP, 1, wa + 2*MELEM);
    addu(qw + 1*WSTEP, 1, wa + 3*MELEM);
    addu(kw + 1*WSTEP, 1, wa + 4*MELEM);
    addu(vw + 1*WSTEP, 1, wa + 5*MELEM);
    addu(qw + 2*WSTEP, 1, wa + 6*MELEM);
    addu(kw + 2*WSTEP, 1, wa + 7*MELEM);
    addu(vw + 2*WSTEP, 1, wa + 8*MELEM);
    addu(ow + 0*WSTEP, 1, wa + 9*MELEM);
    addu(ow + 1*WSTEP, 1, wa + 10*MELEM);
    addu(ow + 2*WSTEP, 1, wa + 11*MELEM);
    addu(w1, 4, wa + 12*MELEM);
    addu(w2, 4, wa + 16*MELEM);
    addu(img,  8, xb);
    addu(ques, 1, quesb);
    addu(kg,   2, kgb);

    dim3 blk(256);
    cvt_units<<<dim3(512, u), blk, 0, stream>>>(ca);

    auto gemm = [&](const unsigned short* A, const unsigned short* W,
                    const float* ba, const float* bb_, const float* bc, const float* bd,
                    unsigned short* C, int M, int N, int K, int relu) {
        dim3 grid(M / 128, N / 128);
        if (relu) gemm_mfma<1><<<grid, blk, 0, stream>>>(
            (const bf16_t*)A, (const bf16_t*)W, ba, bb_, bc, bd, C, M, N, K);
        else      gemm_mfma<0><<<grid, blk, 0, stream>>>(
            (const bf16_t*)A, (const bf16_t*)W, ba, bb_, bc, bd, C, M, N, K);
    };

    // ---- upfront: QKV(t0) + KV(t1) + KV(t2) in ONE grouped dispatch ----
    {
        const int g0 = (NX / 128) * (3072 / 128);       // 1536
        const int g1 = ((B * 64) / 128) * (2048 / 128); // 128
        const int g2 = ((B * 128) / 128) * (2048 / 128);// 256
        gemm_triple<<<dim3(g0 + g1 + g2), blk, 0, stream>>>(
            (const bf16_t*)xb,    (const bf16_t*)(wa + 0*MELEM),
            qb + 0, kb + 0, vb + 0, bQKV, NX, 3072,
            (const bf16_t*)quesb, (const bf16_t*)(wa + 4*MELEM),
            kb + 1024, vb + 1024, bKV1, B * 64, 2048,
            (const bf16_t*)kgb,   (const bf16_t*)(wa + 7*MELEM),
            kb + 2048, vb + 2048, bKV2, B * 128, 2048, 1024);
    }

    const int Lk[3] = {512, 64, 128};
    dim3 ablk(512);
    dim3 agrid(NHEADS, B, 2);

    for (int t = 0; t < 3; ++t) {
        if (t == 0) {
            attn_mfma<0><<<agrid, ablk, 0, stream>>>(
                (const bf16_t*)bQKV, (const bf16_t*)bQKV + 1024, (const bf16_t*)bQKV + 2048,
                3072, 3072, nullptr, bOb, Lk[0]);
        } else {
            // Q projection (input = residual stream xb)
            gemm(xb, wa + (t == 1 ? 3 : 6)*MELEM,
                 qb + t*1024, qb + t*1024, qb + t*1024, qb + t*1024,
                 bQKV, NX, 1024, 1024, 0);
            const unsigned short* kv = (t == 1) ? bKV1 : bKV2;
            attn_mfma<1><<<agrid, ablk, 0, stream>>>(
                (const bf16_t*)bQKV, (const bf16_t*)kv, (const bf16_t*)kv + 1024,
                1024, 2048, (t == 1 ? qmask : kmask), bOb, Lk[t]);
        }
        gemm(bOb, wa + (9 + t)*MELEM,
             ob + t*1024, ob + t*1024, ob + t*1024, ob + t*1024,
             bM, NX, 1024, 1024, 0);
        ln_res_b<0,1><<<NX, blk, 0, stream>>>(xb, bM, lng + t*1024, lnb + t*1024, xb, nullptr);
    }

    // FFN
    gemm(xb, wa + 12*MELEM, b1, b1 + 1024, b1 + 2048, b1 + 3072, hb, NX, FFD, 1024, 1);
    gemm(hb, wa + 16*MELEM, b2, b2, b2, b2, bM, NX, 1024, 4096, 0);
    ln_res_b<1,0><<<NX, blk, 0, stream>>>(xb, bM, lng + 3*1024, lnb + 3*1024, nullptr, out);
}